// Round 4
// baseline (269.056 us; speedup 1.0000x reference)
//
#include <hip/hip_runtime.h>
#include <stdint.h>

// Problem constants (fixed by setup_inputs)
#define NB 16
#define NTF 4096      // frames T
#define ND 512        // feature dim D
#define NS 8192      // note_size (= 2*T)
#define NCOL 40       // 5 + 10 + 25 output columns
#define ROWSB 64      // rows per block
#define BLOCK 256
#define CD 32         // chunk depth in floats of d
#define NCH 16        // 512 / 32

typedef float v4f __attribute__((ext_vector_type(4)));
typedef float v2f __attribute__((ext_vector_type(2)));

// Pack W into Wp2[d4][c][dl]: linear i = d4*160 + c*4 + dl, where d = d4*4+dl.
// A (10-col, 4-d) unit for wave w is 160B contiguous -> 10 consecutive uniform dwordx4.
extern "C" __global__ void pack_w_kernel(const float* __restrict__ Wg,
                                         const float* __restrict__ Wt,
                                         const float* __restrict__ Wf,
                                         float* __restrict__ Wp2)
{
    int i = blockIdx.x * 256 + threadIdx.x;
    if (i >= NCOL * ND) return;
    int d4  = i / 160;
    int rem = i - d4 * 160;
    int c   = rem >> 2;
    int dl  = rem & 3;
    int d   = d4 * 4 + dl;
    float v;
    if (c < 5)       v = Wg[d * 5  + c];
    else if (c < 15) v = Wt[d * 10 + (c - 5)];
    else             v = Wf[d * 25 + (c - 15)];
    Wp2[i] = v;
}

#define GLDS(gp, lp) __builtin_amdgcn_global_load_lds( \
    (const __attribute__((address_space(1))) unsigned int*)(gp), \
    (__attribute__((address_space(3))) unsigned int*)(lp), 16, 0, 0)

// Block: 4 waves x 64 rows (lane = row for every wave). Wave w owns cols [10w,10w+10).
// x: global_load_lds -> LDS, triple-buffered 8KB chunks (2-chunk prefetch distance).
// W: wave-uniform global vector loads (L1-resident 80KB), compiler-scheduled.
// acc: 10 VGPRs/lane. No cross-wave combine; epilogue shares logits via LDS.
extern "C" __global__ void __launch_bounds__(BLOCK, 4)
hier_main(const float* __restrict__ x,
          const float* __restrict__ bg, const float* __restrict__ bt,
          const float* __restrict__ bf,
          const float* __restrict__ Wp2, float* __restrict__ out)
{
    __shared__ __align__(16) float xs[3][512 * 4];   // 3 x 8KB chunk buffers
    __shared__ float Lg[NCOL * ROWSB];               // logits, transposed [c][row], 10KB

    const int t    = threadIdx.x;
    const int lane = t & 63;
    const int w    = t >> 6;
    const int c0   = w * 10;
    const int row0 = blockIdx.x * ROWSB;

    float acc[10];
#pragma unroll
    for (int j = 0; j < 10; ++j) acc[j] = 0.f;

    // wave w stages dq = {w, w+4} of a chunk: 2 GLDS (1KB each), linear dest (rule 21)
    auto stage = [&](int ch, int p) {
#pragma unroll
        for (int k = 0; k < 2; ++k) {
            const int dq = w + k * 4;
            const float* gp = x + (size_t)(row0 + lane) * ND + ch * CD + dq * 4;
            GLDS(gp, (char*)&xs[p][0] + (size_t)(dq * 64) * 16);
        }
    };

    stage(0, 0);
    stage(1, 1);

    int pc = 0;   // ch % 3
    for (int ch = 0; ch < NCH; ++ch) {
        // own S(ch) done (S(ch+1)'s 2 still in flight); raw barrier -> all waves' S(ch) done.
        if (ch < NCH - 1) asm volatile("s_waitcnt vmcnt(2)" ::: "memory");
        else              asm volatile("s_waitcnt vmcnt(0)" ::: "memory");
        __builtin_amdgcn_s_barrier();
        __builtin_amdgcn_sched_barrier(0);
        if (ch < NCH - 2) {
            int ps = pc + 2; if (ps >= 3) ps -= 3;
            stage(ch + 2, ps);          // overwrites buf last read in compute(ch-1): safe past barrier
        }
        __builtin_amdgcn_sched_barrier(0);

        const float* xb = &xs[pc][0];
        const float* wb = Wp2 + (size_t)ch * 1280 + c0 * 4;
#pragma unroll
        for (int dq = 0; dq < 8; ++dq) {
            const v4f x4 = *(const v4f*)(xb + (size_t)(dq * 64 + lane) * 4);  // own-row b128
            const float* wd = wb + dq * 160;
#pragma unroll
            for (int j = 0; j < 10; ++j) {
                const v4f w4 = *(const v4f*)(wd + j * 4);   // wave-uniform 16B broadcast (L1)
                float a = acc[j];
                a = fmaf(x4.x, w4.x, a);
                a = fmaf(x4.y, w4.y, a);
                a = fmaf(x4.z, w4.z, a);
                a = fmaf(x4.w, w4.w, a);
                acc[j] = a;
            }
        }
        pc = (pc + 1 == 3) ? 0 : pc + 1;
    }

    // ---- share logits: Lg[c][row] (lane-consecutive stores/loads: conflict-free) ----
#pragma unroll
    for (int j = 0; j < 10; ++j) Lg[(c0 + j) * 64 + lane] = acc[j];
    __syncthreads();

    // ---- epilogue: every wave computes full chain for its lane-row; writes split by wave ----
    float l[NCOL];
#pragma unroll
    for (int c = 0; c < NCOL; ++c) {
        const float bias = (c < 5) ? bg[c] : ((c < 15) ? bt[c - 5] : bf[c - 15]);
        l[c] = Lg[c * 64 + lane] + bias;
    }

    constexpr int TOWN[10] = {0,1,2,2,2,3,3,3,4,4};
    constexpr int FOWN[25] = {0,1,2,2,2,3,3,3,3,3,3,3,3,4,9,6,8,5,7,1,3,3,3,9,3};

    float gl[5]; int gp = 0; float gbest = -INFINITY;
#pragma unroll
    for (int c = 0; c < 5; ++c) {
        float v = l[c];
        gl[c] = v;
        if (v > gbest) { gbest = v; gp = c; }   // strict > == jnp.argmax first-max
    }
    float tl[10]; int tp = 0; float tbest = -INFINITY;
#pragma unroll
    for (int k = 0; k < 10; ++k) {
        float v = l[5 + k] * ((TOWN[k] == gp) ? 1.f : 0.f);
        tl[k] = v;
        if (v > tbest) { tbest = v; tp = k; }
    }
    float fl[25];
#pragma unroll
    for (int f = 0; f < 25; ++f)
        fl[f] = l[15 + f] * ((FOWN[f] == tp) ? 1.f : 0.f);

    const int r  = row0 + lane;
    const int b  = r >> 12;        // / 4096
    const int tt = r & (NTF - 1);  // % 4096

    if (w == 0) {
        // group_up [B][S][5]: 2 frames x 5 -> 5x float2
        v2f* og = (v2f*)(out + ((size_t)b * NS + 2 * (size_t)tt) * 5);
#pragma unroll
        for (int j = 0; j < 5; ++j) {
            v2f v; v.x = gl[(2 * j) % 5]; v.y = gl[(2 * j + 1) % 5];
            og[j] = v;
        }
    } else if (w == 1) {
        // tech_up [B][S][10]: 2 frames x 10 -> 5x float4
        v4f* ot = (v4f*)(out + (size_t)NB * NS * 5 + ((size_t)b * NS + 2 * (size_t)tt) * 10);
#pragma unroll
        for (int j = 0; j < 5; ++j) {
            v4f v;
            v.x = tl[(4 * j)     % 10];
            v.y = tl[(4 * j + 1) % 10];
            v.z = tl[(4 * j + 2) % 10];
            v.w = tl[(4 * j + 3) % 10];
            ot[j] = v;
        }
    } else if (w == 2) {
        // final_up [B][S][25]: 2 frames x 25 -> 25x float2
        v2f* of = (v2f*)(out + (size_t)NB * NS * 15 + ((size_t)b * NS + 2 * (size_t)tt) * 25);
#pragma unroll
        for (int j = 0; j < 25; ++j) {
            v2f v; v.x = fl[(2 * j) % 25]; v.y = fl[(2 * j + 1) % 25];
            of[j] = v;
        }
    } else {
        // frame_level_final_tech_logits [B][T][25]
        float* ofr = out + (size_t)NB * NS * 40 + ((size_t)b * NTF + tt) * 25;
#pragma unroll
        for (int i = 0; i < 25; ++i) ofr[i] = fl[i];
    }
}

extern "C" void kernel_launch(void* const* d_in, const int* in_sizes, int n_in,
                              void* d_out, int out_size, void* d_ws, size_t ws_size,
                              hipStream_t stream)
{
    const float* x  = (const float*)d_in[0];
    const float* Wg = (const float*)d_in[1];
    const float* bg = (const float*)d_in[2];
    const float* Wt = (const float*)d_in[3];
    const float* bt = (const float*)d_in[4];
    const float* Wf = (const float*)d_in[5];
    const float* bf = (const float*)d_in[6];
    float* Wp2  = (float*)d_ws;          // 40*512*4 = 80 KB packed weights
    float* outp = (float*)d_out;

    hipLaunchKernelGGL(pack_w_kernel, dim3((NCOL * ND + 255) / 256), dim3(256), 0, stream,
                       Wg, Wt, Wf, Wp2);
    hipLaunchKernelGGL(hier_main, dim3((NB * NTF) / ROWSB), dim3(BLOCK), 0, stream,
                       x, bg, bt, bf, Wp2, outp);
}

// Round 5
// 57.480 us; speedup vs baseline: 4.6808x; 4.6808x over previous
//
#include <hip/hip_runtime.h>
#include <stdint.h>

// Problem constants (fixed by setup_inputs)
#define NB 16
#define NTF 4096      // frames T
#define ND 512        // feature dim D
#define NS 8192       // note_size (= 2*T)
#define NCOL 40       // 5 + 10 + 25 output columns
#define ROWSB 64      // rows per block
#define BLOCK 512     // 8 waves
#define NWAVE 8
#define CPW 5         // cols per wave
#define CD 32         // chunk depth (floats of d)
#define NCH 16        // 512 / 32
#define LGS 65        // Lg row stride (65: consecutive c -> distinct banks)

typedef float v4f  __attribute__((ext_vector_type(4)));
typedef float v16f __attribute__((ext_vector_type(16)));

// W pack: Wp3[(u*8 + w)*20 + c*4 + dl] = W[d = u*4+dl][col = w*5+c]
// -> per (wave w, 4-d unit u) slice is 20 contiguous floats (80 B): one
//    s_load_dwordx16 + one s_load_dwordx4.
extern "C" __global__ void pack_w_kernel(const float* __restrict__ Wg,
                                         const float* __restrict__ Wt,
                                         const float* __restrict__ Wf,
                                         float* __restrict__ Wp3)
{
    int o = blockIdx.x * 256 + threadIdx.x;
    if (o >= NCOL * ND) return;
    int s20 = o / 20, r = o % 20;
    int c = r >> 2, dl = r & 3;
    int u = s20 >> 3, w = s20 & 7;
    int d = u * 4 + dl, col = w * 5 + c;
    float v;
    if (col < 5)       v = Wg[d * 5  + col];
    else if (col < 15) v = Wt[d * 10 + (col - 5)];
    else               v = Wf[d * 25 + (col - 15)];
    Wp3[o] = v;
}

#define GLDS(gp, lp) __builtin_amdgcn_global_load_lds( \
    (const __attribute__((address_space(1))) unsigned int*)(gp), \
    (__attribute__((address_space(3))) unsigned int*)(lp), 16, 0, 0)

// W element at flat index 4c+dl from the 20-float bank {C16, C4}
#define WEL(C16, C4, c, dl) \
    ((4*(c)+(dl)) < 16 ? (C16)[4*(c)+(dl)] : (C4)[4*(c)+(dl)-16])

// One pipeline sub-step (4 d-values): wait current bank -> prefetch next bank
// (scalar pipe) -> prefetch next x4 (LDS) -> 20 FMAs vs current bank.
#define SUB(S, C16, C4, N16, N4, PF) do {                                     \
    asm volatile("s_waitcnt lgkmcnt(0)" : "+s"(C16), "+s"(C4) :: "memory");   \
    if (PF) {                                                                 \
        asm volatile("s_load_dwordx16 %0, %2, %3\n\t"                         \
                     "s_load_dwordx4 %1, %2, %4"                              \
            : "=s"(N16), "=s"(N4)                                             \
            : "s"(wch + ((((S)+1) >> 3) * 1280)),                             \
              "i"((((S)+1) & 7) * 640), "i"(((((S)+1) & 7) * 640) + 64));     \
    }                                                                         \
    v4f xcur = xnext;                                                         \
    if ((S) < 7) xnext = *(const v4f*)(xb + (((S)+1)*64 + lane) * 4);         \
    _Pragma("unroll")                                                         \
    for (int c = 0; c < CPW; ++c) {                                           \
        float a = acc[c];                                                     \
        a = fmaf(xcur.x, WEL(C16, C4, c, 0), a);                              \
        a = fmaf(xcur.y, WEL(C16, C4, c, 1), a);                              \
        a = fmaf(xcur.z, WEL(C16, C4, c, 2), a);                              \
        a = fmaf(xcur.w, WEL(C16, C4, c, 3), a);                              \
        acc[c] = a;                                                           \
    }                                                                         \
} while (0)

extern "C" __global__ void __launch_bounds__(BLOCK, 8)
hier_main(const float* __restrict__ x,
          const float* __restrict__ bg, const float* __restrict__ bt,
          const float* __restrict__ bf,
          const float* __restrict__ Wp3, float* __restrict__ out)
{
    __shared__ __align__(16) float xs[3][ROWSB * CD];   // 3 x 8KB x-chunk buffers
    __shared__ float Lg[NCOL * LGS];                    // logits [c][row], 10.4KB

    const int t    = threadIdx.x;
    const int lane = t & 63;
    const int w    = t >> 6;                            // wave 0..7
    const int row0 = blockIdx.x * ROWSB;

    // uniform-by-construction scalars for the SGPR paths
    const int wu    = __builtin_amdgcn_readfirstlane(w);
    const int ldsof = wu * 1024;                        // byte offset in x buffer
    const float* Wp3w = Wp3 + wu * 20;                  // wave's W stream base

    float acc[CPW];
#pragma unroll
    for (int c = 0; c < CPW; ++c) acc[c] = 0.f;

    // stage: wave w loads its 1KB slice (dq = w) of chunk ch into buffer p.
    // slot layout: slot = dq*64 + row  (float4 granularity)
    auto stage = [&](int ch_, int p_) {
        const float* gp = x + (size_t)(row0 + lane) * ND + ch_ * CD + w * 4;
        GLDS(gp, (char*)&xs[p_][0] + ldsof);
    };

    // W bank registers (20 floats each)
    v16f bA16, bB16;
    v4f  bA4,  bB4;

    // prologue: x chunks 0,1 in flight; W bank A (global sub 0) in flight
    stage(0, 0);
    stage(1, 1);
    asm volatile("s_load_dwordx16 %0, %2, 0\n\t"
                 "s_load_dwordx4 %1, %2, 64"
                 : "=s"(bA16), "=s"(bA4) : "s"(Wp3w));

    int pc = 0;
    for (int ch = 0; ch < NCH; ++ch) {
        // own stage(ch) landed (stage(ch+1) may stay in flight)
        if (ch < NCH - 1) asm volatile("s_waitcnt vmcnt(1)" ::: "memory");
        else              asm volatile("s_waitcnt vmcnt(0)" ::: "memory");
        __builtin_amdgcn_s_barrier();       // all waves' slices of chunk ch visible
        __builtin_amdgcn_sched_barrier(0);
        if (ch < NCH - 2) {
            int ps = pc + 2; if (ps >= 3) ps -= 3;
            stage(ch + 2, ps);              // overwrites buffer consumed at ch-1: safe past barrier
        }
        __builtin_amdgcn_sched_barrier(0);

        const float* xb  = &xs[pc][0];
        const float* wch = Wp3w + (size_t)ch * 1280;    // uniform: this chunk's W base
        v4f xnext = *(const v4f*)(xb + lane * 4);       // sub 0 x (exposed once/chunk)

        const bool pf7 = (ch < NCH - 1);    // last global prefetch would be OOB
        SUB(0, bA16, bA4, bB16, bB4, true);
        SUB(1, bB16, bB4, bA16, bA4, true);
        SUB(2, bA16, bA4, bB16, bB4, true);
        SUB(3, bB16, bB4, bA16, bA4, true);
        SUB(4, bA16, bA4, bB16, bB4, true);
        SUB(5, bB16, bB4, bA16, bA4, true);
        SUB(6, bA16, bA4, bB16, bB4, true);
        SUB(7, bB16, bB4, bA16, bA4, pf7);

        pc = (pc + 1 == 3) ? 0 : pc + 1;
    }

    // ---- share logits: Lg[col][row] (lane-consecutive: conflict-free) ----
#pragma unroll
    for (int c = 0; c < CPW; ++c) Lg[(w * CPW + c) * LGS + lane] = acc[c];
    __syncthreads();

    // ---- phase A: per-row bias + hierarchical argmax chain (wave 0) ----
    if (t < 64) {
        constexpr int TOWN[10] = {0,1,2,2,2,3,3,3,4,4};
        constexpr int FOWN[25] = {0,1,2,2,2,3,3,3,3,3,3,3,3,4,9,6,8,5,7,1,3,3,3,9,3};
        const int r = t;
        float gl[5]; int gp = 0; float gbest = -INFINITY;
#pragma unroll
        for (int c = 0; c < 5; ++c) {
            float v = Lg[c * LGS + r] + bg[c];
            gl[c] = v;
            if (v > gbest) { gbest = v; gp = c; }   // strict > == jnp.argmax first-max
        }
        float tl[10]; int tp = 0; float tbest = -INFINITY;
#pragma unroll
        for (int k = 0; k < 10; ++k) {
            float v = (Lg[(5 + k) * LGS + r] + bt[k]) * ((TOWN[k] == gp) ? 1.f : 0.f);
            tl[k] = v;
            if (v > tbest) { tbest = v; tp = k; }
        }
#pragma unroll
        for (int c = 0; c < 5; ++c)  Lg[c * LGS + r] = gl[c];
#pragma unroll
        for (int k = 0; k < 10; ++k) Lg[(5 + k) * LGS + r] = tl[k];
#pragma unroll
        for (int f = 0; f < 25; ++f) {
            float v = (Lg[(15 + f) * LGS + r] + bf[f]) * ((FOWN[f] == tp) ? 1.f : 0.f);
            Lg[(15 + f) * LGS + r] = v;
        }
    }
    __syncthreads();

    // ---- phase B: FULLY COALESCED linear stores (consecutive t -> consecutive
    // floats): each 128B line written by back-to-back instrs of one wave ----
    const int b   = row0 >> 12;
    const int tt0 = row0 & (NTF - 1);

    {   // group_up [B][S][5]: 128 frames x 5 = 640 floats
        float* og = out + ((size_t)b * NS + 2 * (size_t)tt0) * 5;
        for (int i = t; i < 640; i += BLOCK) {
            int s = i / 5, c = i - s * 5;
            og[i] = Lg[c * LGS + (s >> 1)];
        }
    }
    {   // tech_up [B][S][10]: 1280 floats
        float* ot = out + (size_t)NB * NS * 5 + ((size_t)b * NS + 2 * (size_t)tt0) * 10;
        for (int i = t; i < 1280; i += BLOCK) {
            int s = i / 10, c = i - s * 10;
            ot[i] = Lg[(5 + c) * LGS + (s >> 1)];
        }
    }
    {   // final_up [B][S][25]: 3200 floats
        float* of = out + (size_t)NB * NS * 15 + ((size_t)b * NS + 2 * (size_t)tt0) * 25;
        for (int i = t; i < 3200; i += BLOCK) {
            int s = i / 25, c = i - s * 25;
            of[i] = Lg[(15 + c) * LGS + (s >> 1)];
        }
    }
    {   // frame_level_final_tech_logits [B][T][25]: 1600 floats
        float* ofr = out + (size_t)NB * NS * 40 + ((size_t)b * NTF + tt0) * 25;
        for (int i = t; i < 1600; i += BLOCK) {
            int s = i / 25, c = i - s * 25;
            ofr[i] = Lg[(15 + c) * LGS + s];
        }
    }
}

extern "C" void kernel_launch(void* const* d_in, const int* in_sizes, int n_in,
                              void* d_out, int out_size, void* d_ws, size_t ws_size,
                              hipStream_t stream)
{
    const float* x  = (const float*)d_in[0];
    const float* Wg = (const float*)d_in[1];
    const float* bg = (const float*)d_in[2];
    const float* Wt = (const float*)d_in[3];
    const float* bt = (const float*)d_in[4];
    const float* Wf = (const float*)d_in[5];
    const float* bf = (const float*)d_in[6];
    float* Wp3  = (float*)d_ws;          // 40*512*4 = 80 KB packed weights
    float* outp = (float*)d_out;

    hipLaunchKernelGGL(pack_w_kernel, dim3((NCOL * ND + 255) / 256), dim3(256), 0, stream,
                       Wg, Wt, Wf, Wp3);
    hipLaunchKernelGGL(hier_main, dim3((NB * NTF) / ROWSB), dim3(BLOCK), 0, stream,
                       x, bg, bt, bf, Wp3, outp);
}